// Round 12
// baseline (222.021 us; speedup 1.0000x reference)
//
#include <hip/hip_runtime.h>

#define B_    16
#define T_    4096
#define D_    1024
#define CD_   8
#define CS_   1024
#define NROWS 65536
#define EPSF  1e-12f

// ---- d_out float offsets ----
#define OUT_OFF    0
#define COMMIT_OFF 67108864
#define CBLOSS_OFF 67108880
#define IDX_OFF    67108896
#define ZE_OFF     67174432

// ---- ws float offsets ----
#define WS_INWT 0
#define WS_CBR  8192
#define WS_OUTW 16384
#define WS_CN2  24576
#define WS_IDX  25600

template <int CTRL>
static __device__ __forceinline__ float dpp_add(float x) {
    int xi = __builtin_bit_cast(int, x);
    int yi = __builtin_amdgcn_update_dpp(xi, xi, CTRL, 0xF, 0xF, false);
    return x + __builtin_bit_cast(float, yi);
}

// ---------------------------------------------------------------------------
// Prep, 24 blocks x 256 (verbatim)
// ---------------------------------------------------------------------------
__global__ __launch_bounds__(256)
void vq_prep(const float* __restrict__ in_v, const float* __restrict__ in_g,
             const float* __restrict__ out_v, const float* __restrict__ out_g,
             const float* __restrict__ cb, float* __restrict__ ws,
             float* __restrict__ dout) {
    int t = threadIdx.x;
    int blk = blockIdx.x;

    if (blk < 16) {
        __shared__ float s_norm[CD_];
        int lane = t & 63;
        int wid = t >> 6;
        #pragma unroll
        for (int half = 0; half < 2; ++half) {
            int c = wid + half * 4;
            float s = 0.f;
            #pragma unroll
            for (int i = 0; i < D_ / 64; ++i) {
                float v = in_v[(size_t)(lane + 64 * i) * CD_ + c];
                s = fmaf(v, v, s);
            }
            #pragma unroll
            for (int m = 1; m <= 32; m <<= 1) s += __shfl_xor(s, m, 64);
            if (lane == 0) s_norm[c] = sqrtf(s);
        }
        __syncthreads();

        #pragma unroll
        for (int rep = 0; rep < 2; ++rep) {
            int idx = blk * 512 + rep * 256 + t;
            int c = idx >> 10, d = idx & (D_ - 1);
            ws[WS_INWT + idx] = in_g[c] * in_v[(size_t)d * CD_ + c] / fmaxf(EPSF, s_norm[c]);
        }

        if (blk == 0 && t < 32) dout[COMMIT_OFF + t] = 0.f;
    } else if (blk < 20) {
        int j = (blk - 16) * 256 + t;
        float v[CD_]; float s = 0.f;
        #pragma unroll
        for (int c = 0; c < CD_; ++c) { v[c] = cb[j * CD_ + c]; s = fmaf(v[c], v[c], s); }
        float n = fmaxf(EPSF, sqrtf(s));
        float n2 = 0.f;
        #pragma unroll
        for (int c = 0; c < CD_; ++c) {
            float q = v[c] / n;
            ws[WS_CBR + j * CD_ + c] = q;
            n2 = fmaf(q, q, n2);
        }
        ws[WS_CN2 + j] = n2;
    } else {
        int d = (blk - 20) * 256 + t;
        float v[CD_]; float s = 0.f;
        #pragma unroll
        for (int c = 0; c < CD_; ++c) { v[c] = out_v[c * D_ + d]; s = fmaf(v[c], v[c], s); }
        float n = fmaxf(EPSF, sqrtf(s));
        float g = out_g[d];
        #pragma unroll
        for (int c = 0; c < CD_; ++c) ws[WS_OUTW + c * D_ + d] = g * v[c] / n;
    }
}

// ---------------------------------------------------------------------------
// Stage 1: z_e GEMV (R10 verbatim: 512 thr, float2 acc, DPP reduce)
// ---------------------------------------------------------------------------
__global__ __launch_bounds__(512)
void vq_ze(const float* __restrict__ z, const float* __restrict__ in_b,
           const float* __restrict__ ws, float* __restrict__ dout) {
    __shared__ float lds[CD_ * D_];  // in_wT, 32 KB
    int t = threadIdx.x;
    #pragma unroll
    for (int i = 0; i < 4; ++i)
        ((float4*)lds)[i * 512 + t] = ((const float4*)ws)[i * 512 + t];
    __syncthreads();

    int lane = t & 63;
    int wv = (blockIdx.x << 3) + (t >> 6);  // 0..8191

    float bia[CD_];
    #pragma unroll
    for (int c = 0; c < CD_; ++c) bia[c] = in_b[c];

    #pragma unroll
    for (int it = 0; it < 4; ++it) {
        int bi = wv + (it << 13);   // 0..32767
        int row0 = bi << 1;

        float2 acc[2][CD_];
        #pragma unroll
        for (int r = 0; r < 2; ++r)
            #pragma unroll
            for (int c = 0; c < CD_; ++c) acc[r][c] = make_float2(0.f, 0.f);

        #pragma unroll
        for (int k = 0; k < 4; ++k) {
            float4 zv0 = *(const float4*)(z + (size_t)(row0)     * D_ + (k << 8) + (lane << 2));
            float4 zv1 = *(const float4*)(z + (size_t)(row0 + 1) * D_ + (k << 8) + (lane << 2));
            #pragma unroll
            for (int c = 0; c < CD_; ++c) {
                float4 w4 = *(const float4*)(lds + c * D_ + (k << 8) + (lane << 2));
                acc[0][c].x = fmaf(zv0.x, w4.x, acc[0][c].x);
                acc[0][c].y = fmaf(zv0.y, w4.y, acc[0][c].y);
                acc[0][c].x = fmaf(zv0.z, w4.z, acc[0][c].x);
                acc[0][c].y = fmaf(zv0.w, w4.w, acc[0][c].y);
                acc[1][c].x = fmaf(zv1.x, w4.x, acc[1][c].x);
                acc[1][c].y = fmaf(zv1.y, w4.y, acc[1][c].y);
                acc[1][c].x = fmaf(zv1.z, w4.z, acc[1][c].x);
                acc[1][c].y = fmaf(zv1.w, w4.w, acc[1][c].y);
            }
        }

        float ze[2][CD_];
        #pragma unroll
        for (int r = 0; r < 2; ++r) {
            #pragma unroll
            for (int c = 0; c < CD_; ++c) {
                float v = acc[r][c].x + acc[r][c].y;
                v = dpp_add<0xB1>(v);    // + lane^1
                v = dpp_add<0x4E>(v);    // + lane^2
                v = dpp_add<0x124>(v);   // + lane+4 (row_ror:4)
                v = dpp_add<0x128>(v);   // + lane+8 (row_ror:8)
                v += __shfl_xor(v, 16, 64);
                v += __shfl_xor(v, 32, 64);
                ze[r][c] = v + bia[c];
            }
        }

        if (lane == 0) {
            *(float4*)(dout + ZE_OFF + (size_t)row0 * CD_) =
                make_float4(ze[0][0], ze[0][1], ze[0][2], ze[0][3]);
            *(float4*)(dout + ZE_OFF + (size_t)row0 * CD_ + 4) =
                make_float4(ze[0][4], ze[0][5], ze[0][6], ze[0][7]);
        }
        if (lane == 1) {
            *(float4*)(dout + ZE_OFF + (size_t)(row0 + 1) * CD_) =
                make_float4(ze[1][0], ze[1][1], ze[1][2], ze[1][3]);
            *(float4*)(dout + ZE_OFF + (size_t)(row0 + 1) * CD_ + 4) =
                make_float4(ze[1][4], ze[1][5], ze[1][6], ze[1][7]);
        }
    }
}

// ---------------------------------------------------------------------------
// Stage 2: scan, one row per THREAD. Codebook read via wave-uniform scalar
// loads (SMEM pipe) — no LDS, no shuffles in the hot loop. Same score fma
// chain (c=0..7, fmaf(dot,tw,-cn2)) and (strict >, ascending j) first-max
// policy -> indices identical. 256 blocks x 256.
// ---------------------------------------------------------------------------
__global__ __launch_bounds__(256)
void vq_scan(const float* __restrict__ ze_in, const float* __restrict__ cb,
             const float* __restrict__ ws, float* __restrict__ dout,
             int* __restrict__ idx_out) {
    __shared__ float s_loss[4];
    int t = threadIdx.x;
    int lane = t & 63;
    int wid = t >> 6;
    int row = blockIdx.x * 256 + t;

    float4 a  = *(const float4*)(ze_in + (size_t)row * CD_);
    float4 b4 = *(const float4*)(ze_in + (size_t)row * CD_ + 4);

    float s = 0.f;
    s = fmaf(a.x, a.x, s);   s = fmaf(a.y, a.y, s);
    s = fmaf(a.z, a.z, s);   s = fmaf(a.w, a.w, s);
    s = fmaf(b4.x, b4.x, s); s = fmaf(b4.y, b4.y, s);
    s = fmaf(b4.z, b4.z, s); s = fmaf(b4.w, b4.w, s);
    float tw = 2.f / fmaxf(EPSF, sqrtf(s));

    const float* cbw = ws + WS_CBR;   // normalized codebook, row-major
    const float* cw2 = ws + WS_CN2;

    float bs = -1e38f;
    int bj = 0;
    #pragma unroll 4
    for (int j = 0; j < CS_; j += 2) {
        // two codes per iteration: independent dot chains for ILP;
        // operands are wave-uniform -> scalar (SMEM) loads.
        float c00 = cbw[j * 8 + 0], c01 = cbw[j * 8 + 1];
        float c02 = cbw[j * 8 + 2], c03 = cbw[j * 8 + 3];
        float c04 = cbw[j * 8 + 4], c05 = cbw[j * 8 + 5];
        float c06 = cbw[j * 8 + 6], c07 = cbw[j * 8 + 7];
        float c10 = cbw[j * 8 + 8], c11 = cbw[j * 8 + 9];
        float c12 = cbw[j * 8 + 10], c13 = cbw[j * 8 + 11];
        float c14 = cbw[j * 8 + 12], c15 = cbw[j * 8 + 13];
        float c16 = cbw[j * 8 + 14], c17 = cbw[j * 8 + 15];
        float n20 = cw2[j], n21 = cw2[j + 1];

        float d0 = 0.f, d1 = 0.f;
        d0 = fmaf(c00, a.x,  d0);  d1 = fmaf(c10, a.x,  d1);
        d0 = fmaf(c01, a.y,  d0);  d1 = fmaf(c11, a.y,  d1);
        d0 = fmaf(c02, a.z,  d0);  d1 = fmaf(c12, a.z,  d1);
        d0 = fmaf(c03, a.w,  d0);  d1 = fmaf(c13, a.w,  d1);
        d0 = fmaf(c04, b4.x, d0);  d1 = fmaf(c14, b4.x, d1);
        d0 = fmaf(c05, b4.y, d0);  d1 = fmaf(c15, b4.y, d1);
        d0 = fmaf(c06, b4.z, d0);  d1 = fmaf(c16, b4.z, d1);
        d0 = fmaf(c07, b4.w, d0);  d1 = fmaf(c17, b4.w, d1);

        float s0 = fmaf(d0, tw, -n20);
        if (s0 > bs) { bs = s0; bj = j; }
        float s1 = fmaf(d1, tw, -n21);
        if (s1 > bs) { bs = s1; bj = j + 1; }
    }

    // ---- outputs: coalesced per-thread stores ----
    dout[IDX_OFF + row] = (float)bj;
    idx_out[row] = bj;

    // ---- losses: per-thread, wave butterfly, block sum, 2 atomics ----
    float lsum = 0.f;
    {
        const float* q = cb + (size_t)bj * CD_;
        float d0 = a.x  - q[0]; lsum = fmaf(d0, d0, lsum);
        float d1 = a.y  - q[1]; lsum = fmaf(d1, d1, lsum);
        float d2 = a.z  - q[2]; lsum = fmaf(d2, d2, lsum);
        float d3 = a.w  - q[3]; lsum = fmaf(d3, d3, lsum);
        float d4 = b4.x - q[4]; lsum = fmaf(d4, d4, lsum);
        float d5 = b4.y - q[5]; lsum = fmaf(d5, d5, lsum);
        float d6 = b4.z - q[6]; lsum = fmaf(d6, d6, lsum);
        float d7 = b4.w - q[7]; lsum = fmaf(d7, d7, lsum);
    }
    lsum += __shfl_xor(lsum, 1, 64);
    lsum += __shfl_xor(lsum, 2, 64);
    lsum += __shfl_xor(lsum, 4, 64);
    lsum += __shfl_xor(lsum, 8, 64);
    lsum += __shfl_xor(lsum, 16, 64);
    lsum += __shfl_xor(lsum, 32, 64);
    if (lane == 0) s_loss[wid] = lsum;
    __syncthreads();
    if (t == 0) {
        float tot = s_loss[0] + s_loss[1] + s_loss[2] + s_loss[3];
        float v = tot * (1.f / 32768.f);
        int bt = row >> 12;
        atomicAdd(dout + COMMIT_OFF + bt, v);
        atomicAdd(dout + CBLOSS_OFF + bt, v);
    }
}

// ---------------------------------------------------------------------------
// Out projection (verbatim)
// ---------------------------------------------------------------------------
__global__ __launch_bounds__(256)
void vq_out(const float* __restrict__ cb, const float* __restrict__ ws,
            const float* __restrict__ out_b, const int* __restrict__ idx,
            float* __restrict__ out) {
    int t = threadIdx.x;
    int lane = t & 63;
    int wv = (blockIdx.x << 2) + (t >> 6);
    const float* ow = ws + WS_OUTW;

    float4 ob[4];
    #pragma unroll
    for (int k = 0; k < 4; ++k)
        ob[k] = *(const float4*)(out_b + (k << 8) + (lane << 2));

    for (int it = 0; it < 4; ++it) {
        int bi = wv + (it << 12);
        int row0 = bi << 2;

        float zq[4][CD_];
        #pragma unroll
        for (int r = 0; r < 4; ++r) {
            int j = idx[row0 + r];
            #pragma unroll
            for (int c = 0; c < CD_; ++c) zq[r][c] = cb[j * CD_ + c];
        }

        #pragma unroll
        for (int k = 0; k < 4; ++k) {
            float4 a0 = ob[k], a1 = ob[k], a2 = ob[k], a3 = ob[k];
            #pragma unroll
            for (int c = 0; c < CD_; ++c) {
                float4 w4 = *(const float4*)(ow + c * D_ + (k << 8) + (lane << 2));
                a0.x = fmaf(zq[0][c], w4.x, a0.x); a0.y = fmaf(zq[0][c], w4.y, a0.y);
                a0.z = fmaf(zq[0][c], w4.z, a0.z); a0.w = fmaf(zq[0][c], w4.w, a0.w);
                a1.x = fmaf(zq[1][c], w4.x, a1.x); a1.y = fmaf(zq[1][c], w4.y, a1.y);
                a1.z = fmaf(zq[1][c], w4.z, a1.z); a1.w = fmaf(zq[1][c], w4.w, a1.w);
                a2.x = fmaf(zq[2][c], w4.x, a2.x); a2.y = fmaf(zq[2][c], w4.y, a2.y);
                a2.z = fmaf(zq[2][c], w4.z, a2.z); a2.w = fmaf(zq[2][c], w4.w, a2.w);
                a3.x = fmaf(zq[3][c], w4.x, a3.x); a3.y = fmaf(zq[3][c], w4.y, a3.y);
                a3.z = fmaf(zq[3][c], w4.z, a3.z); a3.w = fmaf(zq[3][c], w4.w, a3.w);
            }
            size_t base = (size_t)row0 * D_ + (k << 8) + (lane << 2);
            *(float4*)(out + base)            = a0;
            *(float4*)(out + base + D_)       = a1;
            *(float4*)(out + base + 2 * D_)   = a2;
            *(float4*)(out + base + 3 * D_)   = a3;
        }
    }
}

extern "C" void kernel_launch(void* const* d_in, const int* in_sizes, int n_in,
                              void* d_out, int out_size, void* d_ws, size_t ws_size,
                              hipStream_t stream) {
    const float* z     = (const float*)d_in[0];
    const float* in_v  = (const float*)d_in[1];
    const float* in_g  = (const float*)d_in[2];
    const float* in_b  = (const float*)d_in[3];
    const float* out_v = (const float*)d_in[4];
    const float* out_g = (const float*)d_in[5];
    const float* out_b = (const float*)d_in[6];
    const float* cb    = (const float*)d_in[7];
    float* dout = (float*)d_out;
    float* ws   = (float*)d_ws;
    int* idxp   = (int*)(ws + WS_IDX);

    vq_prep<<<24, 256, 0, stream>>>(in_v, in_g, out_v, out_g, cb, ws, dout);
    vq_ze<<<1024, 512, 0, stream>>>(z, in_b, ws, dout);
    vq_scan<<<256, 256, 0, stream>>>(dout + ZE_OFF, cb, ws, dout, idxp);
    vq_out<<<1024, 256, 0, stream>>>(cb, ws, out_b, idxp, dout + OUT_OFF);
}

// Round 13
// 177.920 us; speedup vs baseline: 1.2479x; 1.2479x over previous
//
#include <hip/hip_runtime.h>

#define B_    16
#define T_    4096
#define D_    1024
#define CD_   8
#define CS_   1024
#define NROWS 65536
#define EPSF  1e-12f

// ---- d_out float offsets ----
#define OUT_OFF    0
#define COMMIT_OFF 67108864
#define CBLOSS_OFF 67108880
#define IDX_OFF    67108896
#define ZE_OFF     67174432

// ---- ws float offsets ----
#define WS_INWT 0
#define WS_CBR  8192
#define WS_OUTW 16384
#define WS_CN2  24576
#define WS_IDX  25600

template <int CTRL>
static __device__ __forceinline__ float dpp_add(float x) {
    int xi = __builtin_bit_cast(int, x);
    int yi = __builtin_amdgcn_update_dpp(xi, xi, CTRL, 0xF, 0xF, false);
    return x + __builtin_bit_cast(float, yi);
}

// ---------------------------------------------------------------------------
// Prep, 24 blocks x 256 (verbatim)
// ---------------------------------------------------------------------------
__global__ __launch_bounds__(256)
void vq_prep(const float* __restrict__ in_v, const float* __restrict__ in_g,
             const float* __restrict__ out_v, const float* __restrict__ out_g,
             const float* __restrict__ cb, float* __restrict__ ws,
             float* __restrict__ dout) {
    int t = threadIdx.x;
    int blk = blockIdx.x;

    if (blk < 16) {
        __shared__ float s_norm[CD_];
        int lane = t & 63;
        int wid = t >> 6;
        #pragma unroll
        for (int half = 0; half < 2; ++half) {
            int c = wid + half * 4;
            float s = 0.f;
            #pragma unroll
            for (int i = 0; i < D_ / 64; ++i) {
                float v = in_v[(size_t)(lane + 64 * i) * CD_ + c];
                s = fmaf(v, v, s);
            }
            #pragma unroll
            for (int m = 1; m <= 32; m <<= 1) s += __shfl_xor(s, m, 64);
            if (lane == 0) s_norm[c] = sqrtf(s);
        }
        __syncthreads();

        #pragma unroll
        for (int rep = 0; rep < 2; ++rep) {
            int idx = blk * 512 + rep * 256 + t;
            int c = idx >> 10, d = idx & (D_ - 1);
            ws[WS_INWT + idx] = in_g[c] * in_v[(size_t)d * CD_ + c] / fmaxf(EPSF, s_norm[c]);
        }

        if (blk == 0 && t < 32) dout[COMMIT_OFF + t] = 0.f;
    } else if (blk < 20) {
        int j = (blk - 16) * 256 + t;
        float v[CD_]; float s = 0.f;
        #pragma unroll
        for (int c = 0; c < CD_; ++c) { v[c] = cb[j * CD_ + c]; s = fmaf(v[c], v[c], s); }
        float n = fmaxf(EPSF, sqrtf(s));
        float n2 = 0.f;
        #pragma unroll
        for (int c = 0; c < CD_; ++c) {
            float q = v[c] / n;
            ws[WS_CBR + j * CD_ + c] = q;
            n2 = fmaf(q, q, n2);
        }
        ws[WS_CN2 + j] = n2;
    } else {
        int d = (blk - 20) * 256 + t;
        float v[CD_]; float s = 0.f;
        #pragma unroll
        for (int c = 0; c < CD_; ++c) { v[c] = out_v[c * D_ + d]; s = fmaf(v[c], v[c], s); }
        float n = fmaxf(EPSF, sqrtf(s));
        float g = out_g[d];
        #pragma unroll
        for (int c = 0; c < CD_; ++c) ws[WS_OUTW + c * D_ + d] = g * v[c] / n;
    }
}

// ---------------------------------------------------------------------------
// Stage 1: z_e GEMV, weights REGISTER-RESIDENT (32 x float4 per lane, loaded
// once). No LDS, no barrier, no ds_read in the loop. FMA values/order
// identical to R10 -> bit-exact z_e.
// ---------------------------------------------------------------------------
__global__ __launch_bounds__(256)
void vq_ze(const float* __restrict__ z, const float* __restrict__ in_b,
           const float* __restrict__ ws, float* __restrict__ dout) {
    int t = threadIdx.x;
    int lane = t & 63;
    int wv = (blockIdx.x << 2) + (t >> 6);  // 0..8191

    // per-lane weight slice: w[c][k] = in_wT[c][k*256 + lane*4 .. +3]
    float4 w[CD_][4];
    #pragma unroll
    for (int c = 0; c < CD_; ++c)
        #pragma unroll
        for (int k = 0; k < 4; ++k)
            w[c][k] = *(const float4*)(ws + WS_INWT + c * D_ + (k << 8) + (lane << 2));

    float bia[CD_];
    #pragma unroll
    for (int c = 0; c < CD_; ++c) bia[c] = in_b[c];

    #pragma unroll
    for (int it = 0; it < 4; ++it) {
        int bi = wv + (it << 13);   // 0..32767
        int row0 = bi << 1;

        float2 acc[2][CD_];
        #pragma unroll
        for (int r = 0; r < 2; ++r)
            #pragma unroll
            for (int c = 0; c < CD_; ++c) acc[r][c] = make_float2(0.f, 0.f);

        #pragma unroll
        for (int k = 0; k < 4; ++k) {
            float4 zv0 = *(const float4*)(z + (size_t)(row0)     * D_ + (k << 8) + (lane << 2));
            float4 zv1 = *(const float4*)(z + (size_t)(row0 + 1) * D_ + (k << 8) + (lane << 2));
            #pragma unroll
            for (int c = 0; c < CD_; ++c) {
                acc[0][c].x = fmaf(zv0.x, w[c][k].x, acc[0][c].x);
                acc[0][c].y = fmaf(zv0.y, w[c][k].y, acc[0][c].y);
                acc[0][c].x = fmaf(zv0.z, w[c][k].z, acc[0][c].x);
                acc[0][c].y = fmaf(zv0.w, w[c][k].w, acc[0][c].y);
                acc[1][c].x = fmaf(zv1.x, w[c][k].x, acc[1][c].x);
                acc[1][c].y = fmaf(zv1.y, w[c][k].y, acc[1][c].y);
                acc[1][c].x = fmaf(zv1.z, w[c][k].z, acc[1][c].x);
                acc[1][c].y = fmaf(zv1.w, w[c][k].w, acc[1][c].y);
            }
        }

        float ze[2][CD_];
        #pragma unroll
        for (int r = 0; r < 2; ++r) {
            #pragma unroll
            for (int c = 0; c < CD_; ++c) {
                float v = acc[r][c].x + acc[r][c].y;
                v = dpp_add<0xB1>(v);    // + lane^1
                v = dpp_add<0x4E>(v);    // + lane^2
                v = dpp_add<0x124>(v);   // + lane+4 (row_ror:4)
                v = dpp_add<0x128>(v);   // + lane+8 (row_ror:8)
                v += __shfl_xor(v, 16, 64);
                v += __shfl_xor(v, 32, 64);
                ze[r][c] = v + bia[c];
            }
        }

        if (lane == 0) {
            *(float4*)(dout + ZE_OFF + (size_t)row0 * CD_) =
                make_float4(ze[0][0], ze[0][1], ze[0][2], ze[0][3]);
            *(float4*)(dout + ZE_OFF + (size_t)row0 * CD_ + 4) =
                make_float4(ze[0][4], ze[0][5], ze[0][6], ze[0][7]);
        }
        if (lane == 1) {
            *(float4*)(dout + ZE_OFF + (size_t)(row0 + 1) * CD_) =
                make_float4(ze[1][0], ze[1][1], ze[1][2], ze[1][3]);
            *(float4*)(dout + ZE_OFF + (size_t)(row0 + 1) * CD_ + 4) =
                make_float4(ze[1][4], ze[1][5], ze[1][6], ze[1][7]);
        }
    }
}

// ---------------------------------------------------------------------------
// Stage 2: scan (R10 verbatim: 2048 blocks, 8 threads/row, LDS codebook)
// ---------------------------------------------------------------------------
__global__ __launch_bounds__(256)
void vq_scan(const float* __restrict__ ze_in, const float* __restrict__ cb,
             const float* __restrict__ ws, float* __restrict__ dout,
             int* __restrict__ idx_out) {
    __shared__ float s_cb[CS_ * CD_];  // 32 KB
    __shared__ float s_c2[CS_];        // 4 KB
    __shared__ float s_loss[4];
    int t = threadIdx.x;
    #pragma unroll
    for (int i = 0; i < 8; ++i)
        ((float4*)s_cb)[i * 256 + t] = ((const float4*)(ws + WS_CBR))[i * 256 + t];
    ((float4*)s_c2)[t] = ((const float4*)(ws + WS_CN2))[t];
    __syncthreads();

    int lane = t & 63;
    int wid = t >> 6;
    int r = t >> 3;
    int sub = t & 7;
    int row = blockIdx.x * 32 + r;

    float4 a  = *(const float4*)(ze_in + (size_t)row * CD_);
    float4 b4 = *(const float4*)(ze_in + (size_t)row * CD_ + 4);

    float s = 0.f;
    s = fmaf(a.x, a.x, s);   s = fmaf(a.y, a.y, s);
    s = fmaf(a.z, a.z, s);   s = fmaf(a.w, a.w, s);
    s = fmaf(b4.x, b4.x, s); s = fmaf(b4.y, b4.y, s);
    s = fmaf(b4.z, b4.z, s); s = fmaf(b4.w, b4.w, s);
    float tw = 2.f / fmaxf(EPSF, sqrtf(s));

    float bs = -1e38f;
    int bj = 0;
    #pragma unroll 4
    for (int jj = 0; jj < 128; ++jj) {
        int j = (jj << 3) + sub;
        float4 ca  = ((const float4*)s_cb)[j * 2];
        float4 cbv = ((const float4*)s_cb)[j * 2 + 1];
        float2 dp = make_float2(0.f, 0.f);
        dp.x = fmaf(ca.x,  a.x,  dp.x);
        dp.y = fmaf(ca.y,  a.y,  dp.y);
        dp.x = fmaf(ca.z,  a.z,  dp.x);
        dp.y = fmaf(ca.w,  a.w,  dp.y);
        dp.x = fmaf(cbv.x, b4.x, dp.x);
        dp.y = fmaf(cbv.y, b4.y, dp.y);
        dp.x = fmaf(cbv.z, b4.z, dp.x);
        dp.y = fmaf(cbv.w, b4.w, dp.y);
        float dot = dp.x + dp.y;
        float sc = fmaf(dot, tw, -s_c2[j]);
        if (sc > bs || (sc == bs && j < bj)) { bs = sc; bj = j; }
    }
    #pragma unroll
    for (int m = 1; m <= 4; m <<= 1) {
        float os = __shfl_xor(bs, m, 64);
        int   oj = __shfl_xor(bj, m, 64);
        bool take = (os > bs) || (os == bs && oj < bj);
        bs = take ? os : bs;
        bj = take ? oj : bj;
    }

    float lsum = 0.f;
    if (sub == 0) {
        const float* q = cb + (size_t)bj * CD_;
        float d0 = a.x  - q[0]; lsum = fmaf(d0, d0, lsum);
        float d1 = a.y  - q[1]; lsum = fmaf(d1, d1, lsum);
        float d2 = a.z  - q[2]; lsum = fmaf(d2, d2, lsum);
        float d3 = a.w  - q[3]; lsum = fmaf(d3, d3, lsum);
        float d4 = b4.x - q[4]; lsum = fmaf(d4, d4, lsum);
        float d5 = b4.y - q[5]; lsum = fmaf(d5, d5, lsum);
        float d6 = b4.z - q[6]; lsum = fmaf(d6, d6, lsum);
        float d7 = b4.w - q[7]; lsum = fmaf(d7, d7, lsum);
    }
    lsum += __shfl_xor(lsum, 1, 64);
    lsum += __shfl_xor(lsum, 2, 64);
    lsum += __shfl_xor(lsum, 4, 64);
    lsum += __shfl_xor(lsum, 8, 64);
    lsum += __shfl_xor(lsum, 16, 64);
    lsum += __shfl_xor(lsum, 32, 64);
    if (lane == 0) s_loss[wid] = lsum;

    if (sub == 0) {
        dout[IDX_OFF + row] = (float)bj;
        idx_out[row] = bj;
    }
    __syncthreads();
    if (t == 0) {
        float tot = s_loss[0] + s_loss[1] + s_loss[2] + s_loss[3];
        float v = tot * (1.f / 32768.f);
        int bt = row >> 12;
        atomicAdd(dout + COMMIT_OFF + bt, v);
        atomicAdd(dout + CBLOSS_OFF + bt, v);
    }
}

// ---------------------------------------------------------------------------
// Out projection, weights REGISTER-RESIDENT (loaded once per lane). Same
// float values / fma order as before -> bit-exact out.
// ---------------------------------------------------------------------------
__global__ __launch_bounds__(256)
void vq_out(const float* __restrict__ cb, const float* __restrict__ ws,
            const float* __restrict__ out_b, const int* __restrict__ idx,
            float* __restrict__ out) {
    int t = threadIdx.x;
    int lane = t & 63;
    int wv = (blockIdx.x << 2) + (t >> 6);

    // per-lane weight slice: w[c][k] = out_w[c][k*256 + lane*4 .. +3]
    float4 w[CD_][4];
    #pragma unroll
    for (int c = 0; c < CD_; ++c)
        #pragma unroll
        for (int k = 0; k < 4; ++k)
            w[c][k] = *(const float4*)(ws + WS_OUTW + c * D_ + (k << 8) + (lane << 2));

    float4 ob[4];
    #pragma unroll
    for (int k = 0; k < 4; ++k)
        ob[k] = *(const float4*)(out_b + (k << 8) + (lane << 2));

    for (int it = 0; it < 4; ++it) {
        int bi = wv + (it << 12);
        int row0 = bi << 2;

        float zq[4][CD_];
        #pragma unroll
        for (int r = 0; r < 4; ++r) {
            int j = idx[row0 + r];
            #pragma unroll
            for (int c = 0; c < CD_; ++c) zq[r][c] = cb[j * CD_ + c];
        }

        #pragma unroll
        for (int k = 0; k < 4; ++k) {
            float4 a0 = ob[k], a1 = ob[k], a2 = ob[k], a3 = ob[k];
            #pragma unroll
            for (int c = 0; c < CD_; ++c) {
                a0.x = fmaf(zq[0][c], w[c][k].x, a0.x); a0.y = fmaf(zq[0][c], w[c][k].y, a0.y);
                a0.z = fmaf(zq[0][c], w[c][k].z, a0.z); a0.w = fmaf(zq[0][c], w[c][k].w, a0.w);
                a1.x = fmaf(zq[1][c], w[c][k].x, a1.x); a1.y = fmaf(zq[1][c], w[c][k].y, a1.y);
                a1.z = fmaf(zq[1][c], w[c][k].z, a1.z); a1.w = fmaf(zq[1][c], w[c][k].w, a1.w);
                a2.x = fmaf(zq[2][c], w[c][k].x, a2.x); a2.y = fmaf(zq[2][c], w[c][k].y, a2.y);
                a2.z = fmaf(zq[2][c], w[c][k].z, a2.z); a2.w = fmaf(zq[2][c], w[c][k].w, a2.w);
                a3.x = fmaf(zq[3][c], w[c][k].x, a3.x); a3.y = fmaf(zq[3][c], w[c][k].y, a3.y);
                a3.z = fmaf(zq[3][c], w[c][k].z, a3.z); a3.w = fmaf(zq[3][c], w[c][k].w, a3.w);
            }
            size_t base = (size_t)row0 * D_ + (k << 8) + (lane << 2);
            *(float4*)(out + base)            = a0;
            *(float4*)(out + base + D_)       = a1;
            *(float4*)(out + base + 2 * D_)   = a2;
            *(float4*)(out + base + 3 * D_)   = a3;
        }
    }
}

extern "C" void kernel_launch(void* const* d_in, const int* in_sizes, int n_in,
                              void* d_out, int out_size, void* d_ws, size_t ws_size,
                              hipStream_t stream) {
    const float* z     = (const float*)d_in[0];
    const float* in_v  = (const float*)d_in[1];
    const float* in_g  = (const float*)d_in[2];
    const float* in_b  = (const float*)d_in[3];
    const float* out_v = (const float*)d_in[4];
    const float* out_g = (const float*)d_in[5];
    const float* out_b = (const float*)d_in[6];
    const float* cb    = (const float*)d_in[7];
    float* dout = (float*)d_out;
    float* ws   = (float*)d_ws;
    int* idxp   = (int*)(ws + WS_IDX);

    vq_prep<<<24, 256, 0, stream>>>(in_v, in_g, out_v, out_g, cb, ws, dout);
    vq_ze<<<2048, 256, 0, stream>>>(z, in_b, ws, dout);
    vq_scan<<<2048, 256, 0, stream>>>(dout + ZE_OFF, cb, ws, dout, idxp);
    vq_out<<<1024, 256, 0, stream>>>(cb, ws, out_b, idxp, dout + OUT_OFF);
}